// Round 1
// baseline (493.600 us; speedup 1.0000x reference)
//
#include <hip/hip_runtime.h>

typedef unsigned short u16;
typedef float f32x4 __attribute__((ext_vector_type(4)));
typedef short bf16x8 __attribute__((ext_vector_type(8)));

#define DHW 131072            // 32*64*64
// packed-weight offsets in ushort units inside d_ws
#define OFF_WQ 0
#define OFF_WK 16384
#define OFF_WV 32768
#define OFF_WO 49152
#define OFF_W1 65536
#define OFF_W2 131072
// total 196608 u16 = 384 KB of d_ws

__device__ __forceinline__ float b2f(u16 u){ union{unsigned i; float f;} x; x.i=((unsigned)u)<<16; return x.f; }
__device__ __forceinline__ u16 f2b(float f){ union{float f; unsigned u;} x; x.f=f; unsigned r=x.u+0x7fffu+((x.u>>16)&1u); return (u16)(r>>16); }
// swizzled ushort index into a [64 tokens][128 ch] bf16 LDS buffer (16B cells, cell^=(t&7))
__device__ __forceinline__ int swi(int t, int c){ return (t<<7) + (((c>>3) ^ (t&7))<<3) + (c&7); }

// ---------------- weight pack kernel: fp32 [K][N] -> bf16 MFMA B-fragments ----------------
// b-frag for (nt,ks): lane l holds B[ks*32 + (l>>4)*8 + j][nt*16 + (l&15)], j=0..7 (16B/lane)
__global__ void pack_w(const float* __restrict__ Wq, const float* __restrict__ Wk,
                       const float* __restrict__ Wv, const float* __restrict__ Wo,
                       const float* __restrict__ W1, const float* __restrict__ W2,
                       u16* __restrict__ ws){
  int tid = blockIdx.x*256 + threadIdx.x;       // 0..24575
  const float* src; int dst, K, N, fb;
  if      (tid <  2048){ src=Wq; dst=OFF_WQ; K=128; N=128; fb=tid;       }
  else if (tid <  4096){ src=Wk; dst=OFF_WK; K=128; N=128; fb=tid-2048;  }
  else if (tid <  6144){ src=Wv; dst=OFF_WV; K=128; N=128; fb=tid-4096;  }
  else if (tid <  8192){ src=Wo; dst=OFF_WO; K=128; N=128; fb=tid-6144;  }
  else if (tid < 16384){ src=W1; dst=OFF_W1; K=128; N=512; fb=tid-8192;  }
  else                 { src=W2; dst=OFF_W2; K=512; N=128; fb=tid-16384; }
  int l = fb & 63, f = fb >> 6;
  int ksc = K >> 5;
  int nt = f / ksc, ks = f - nt*ksc;
  int k0 = ks*32 + ((l>>4)<<3);
  int col = nt*16 + (l&15);
  union { uint4 v; u16 u[8]; } pk;
  #pragma unroll
  for (int j=0;j<8;j++) pk.u[j] = f2b(src[(k0+j)*N + col]);
  *reinterpret_cast<uint4*>(ws + dst + f*512 + l*8) = pk.v;
}

// ---------------- MFMA micro-GEMM helpers (per wave: 4 m-tiles x 2 n-tiles) ----------------
__device__ __forceinline__ void zacc(f32x4 (&a)[4][2]){
  #pragma unroll
  for (int i=0;i<4;i++){ a[i][0]=(f32x4){0.f,0.f,0.f,0.f}; a[i][1]=(f32x4){0.f,0.f,0.f,0.f}; }
}
// K=128 matmul: A = swizzled LDS [64][128] bf16, B = packed frags (ksc=4)
__device__ __forceinline__ void mm128(const u16* __restrict__ aus, const u16* __restrict__ wsm,
                                      int ntb, int l, f32x4 (&acc)[4][2]){
  #pragma unroll
  for (int ks=0; ks<4; ++ks){
    bf16x8 b0 = *(const bf16x8*)(wsm + ((ntb+0)*4 + ks)*512 + l*8);
    bf16x8 b1 = *(const bf16x8*)(wsm + ((ntb+1)*4 + ks)*512 + l*8);
    int g = ks*4 + (l>>4);
    #pragma unroll
    for (int mt=0; mt<4; ++mt){
      int tt = mt*16 + (l&15);
      bf16x8 a = *(const bf16x8*)(aus + (tt<<7) + ((g ^ (tt&7))<<3));
      acc[mt][0] = __builtin_amdgcn_mfma_f32_16x16x32_bf16(a, b0, acc[mt][0], 0,0,0);
      acc[mt][1] = __builtin_amdgcn_mfma_f32_16x16x32_bf16(a, b1, acc[mt][1], 0,0,0);
    }
  }
}
// FFN2 partial: W2 packed with ksc=16, local k-chunk ch (global ks = ch*4+ks)
__device__ __forceinline__ void mm128_w2(const u16* __restrict__ aus, const u16* __restrict__ wsm,
                                         int ntb, int ch, int l, f32x4 (&acc)[4][2]){
  #pragma unroll
  for (int ks=0; ks<4; ++ks){
    int gks = ch*4 + ks;
    bf16x8 b0 = *(const bf16x8*)(wsm + ((ntb+0)*16 + gks)*512 + l*8);
    bf16x8 b1 = *(const bf16x8*)(wsm + ((ntb+1)*16 + gks)*512 + l*8);
    int g = ks*4 + (l>>4);
    #pragma unroll
    for (int mt=0; mt<4; ++mt){
      int tt = mt*16 + (l&15);
      bf16x8 a = *(const bf16x8*)(aus + (tt<<7) + ((g ^ (tt&7))<<3));
      acc[mt][0] = __builtin_amdgcn_mfma_f32_16x16x32_bf16(a, b0, acc[mt][0], 0,0,0);
      acc[mt][1] = __builtin_amdgcn_mfma_f32_16x16x32_bf16(a, b1, acc[mt][1], 0,0,0);
    }
  }
}
// epilogue: acc + bias -> bf16 LDS at C-layout coords
__device__ __forceinline__ void epi_store(u16* dst, f32x4 (&acc)[4][2], const float* bias,
                                          int l, int n0w){
  #pragma unroll
  for (int mt=0;mt<4;mt++)
  #pragma unroll
  for (int nt=0;nt<2;nt++)
  #pragma unroll
  for (int r=0;r<4;r++){
    int tt = mt*16 + ((l>>4)<<2) + r;
    int cc = n0w + nt*16 + (l&15);
    dst[swi(tt,cc)] = f2b(acc[mt][nt][r] + bias[cc]);
  }
}
// read 16 consecutive channels (c0 multiple of 16) of row t into fp32
__device__ __forceinline__ void load16(const u16* buf, int t, int c0, float* o){
  int g = c0 >> 3;
  union { uint4 v; u16 u[8]; } a, b;
  a.v = *(const uint4*)&buf[(t<<7) + (( g    ^ (t&7))<<3)];
  b.v = *(const uint4*)&buf[(t<<7) + (((g+1) ^ (t&7))<<3)];
  #pragma unroll
  for (int j=0;j<8;j++){ o[j]=b2f(a.u[j]); o[8+j]=b2f(b.u[j]); }
}

// ---------------- fused kernel: 1 block = 64 tokens, 256 threads ----------------
__global__ __launch_bounds__(256,2) void fused(
    const float* __restrict__ x, const float* __restrict__ pol,
    const float* __restrict__ Wp, const u16* __restrict__ ws,
    const float* __restrict__ bp, const float* __restrict__ bq,
    const float* __restrict__ bk, const float* __restrict__ bv,
    const float* __restrict__ bo, const float* __restrict__ bf1,
    const float* __restrict__ bf2, const float* __restrict__ g1,
    const float* __restrict__ be1, const float* __restrict__ g2,
    const float* __restrict__ be2, float* __restrict__ out)
{
  __shared__ __align__(16) unsigned char arena[61952];
  u16*   xn_us = (u16*)  (arena);           // 16384 B: xn -> V -> hnorm
  u16*   q_us  = (u16*)  (arena + 16384);   // 16384 B: xp -> Q -> attended
  float* red   = (float*)(arena + 32768);   // 2048 B
  float* stats = (float*)(arena + 34816);   // 512 B
  u16*   k_us  = (u16*)  (arena + 35328);   // 16384 B: K -> out(res2 copy) -> h1 chunks
  float* wp    = (float*)(arena + 51712);   // 3072 B
  float* bias  = (float*)(arena + 54784);   // 7168 B
  // final fp32 [64][129] output staging overlays arena[0..33024) (xn/q/red dead then)

  const int tid = threadIdx.x;
  const int t   = tid & 63;       // token in tile (also: lane within wave)
  const int p   = tid >> 6;       // quarter (also: wave id)
  const int l   = t;
  const int n0w = p*32;

  // ---- load biases / gammas / Wp into LDS ----
  {
    int o = tid & 127;
    if ((tid>>7)==0){ bias[o]=bp[o]; bias[256+o]=bk[o]; bias[512+o]=bo[o]; bias[768+o]=g1[o]; bias[1024+o]=g2[o]; }
    else            { bias[128+o]=bq[o]; bias[384+o]=bv[o]; bias[640+o]=bf2[o]; bias[896+o]=be1[o]; bias[1152+o]=be2[o]; }
    for (int i=tid;i<512;i+=256) bias[1280+i]=bf1[i];
    for (int i=tid;i<768;i+=256) wp[i]=Wp[i];
  }
  const int bi   = (int)((blockIdx.x*64) >> 17);       // batch index (DHW = 2^17)
  const int dhw0 = (int)((blockIdx.x*64) & (DHW-1));
  const float* xb = x   + (size_t)bi*128*DHW + dhw0;
  const float* pb = pol + (size_t)bi*6*DHW + dhw0;
  float pl6[6];
  #pragma unroll
  for (int j=0;j<6;j++) pl6[j] = pb[(size_t)j*DHW + t];
  __syncthreads();

  // ---- stage x, compute xp = x + polar@Wp + bp; LN1 partial sums ----
  float xp[32]; float s1=0.f, s2=0.f;
  #pragma unroll
  for (int it=0; it<32; ++it){
    int c = p*32 + it;
    float a = xb[(size_t)c*DHW + t] + bias[c];
    #pragma unroll
    for (int j=0;j<6;j++) a = fmaf(pl6[j], wp[j*128+c], a);
    xp[it]=a; s1+=a; s2+=a*a;
  }
  #pragma unroll
  for (int cl=0; cl<4; ++cl){             // xp -> q_us (bf16, cell-packed)
    union { uint4 v; u16 u[8]; } pk;
    #pragma unroll
    for (int j=0;j<8;j++) pk.u[j]=f2b(xp[cl*8+j]);
    int g = p*4+cl;
    *(uint4*)&q_us[(t<<7) + ((g ^ (t&7))<<3)] = pk.v;
  }
  red[p*64+t]=s1; red[256+p*64+t]=s2;
  __syncthreads();
  if (tid < 64){
    float a=0.f,b=0.f;
    #pragma unroll
    for (int i=0;i<4;i++){ a+=red[i*64+tid]; b+=red[256+i*64+tid]; }
    float m=a*0.0078125f, v=b*0.0078125f-m*m;
    stats[tid*2]=m; stats[tid*2+1]=rsqrtf(v+1e-5f);
  }
  __syncthreads();
  {  // xn = LN1(xp)*g1+beta1 -> xn_us
    float mn=stats[t*2], rs=stats[t*2+1];
    #pragma unroll
    for (int cl=0; cl<4; ++cl){
      union { uint4 v; u16 u[8]; } pk;
      #pragma unroll
      for (int j=0;j<8;j++){ int c=p*32+cl*8+j; pk.u[j]=f2b((xp[cl*8+j]-mn)*rs*bias[768+c]+bias[896+c]); }
      int g = p*4+cl;
      *(uint4*)&xn_us[(t<<7) + ((g ^ (t&7))<<3)] = pk.v;
    }
  }
  __syncthreads();
  // ---- each wave caches residual at its own C-tile coords (32 regs) ----
  float res[32];
  #pragma unroll
  for (int mt=0;mt<4;mt++)
  #pragma unroll
  for (int nt=0;nt<2;nt++)
  #pragma unroll
  for (int r=0;r<4;r++){
    int tt = mt*16 + ((l>>4)<<2) + r;
    int cc = n0w + nt*16 + (l&15);
    res[mt*8+nt*4+r] = b2f(q_us[swi(tt,cc)]);
  }
  __syncthreads();

  // ---- QKV ----
  f32x4 acc[4][2];
  zacc(acc); mm128(xn_us, ws+OFF_WQ, p*2, l, acc); epi_store(q_us, acc, bias+128, l, n0w);
  zacc(acc); mm128(xn_us, ws+OFF_WK, p*2, l, acc); epi_store(k_us, acc, bias+256, l, n0w);
  zacc(acc); mm128(xn_us, ws+OFF_WV, p*2, l, acc);
  __syncthreads();                         // all xn reads done
  epi_store(xn_us, acc, bias+384, l, n0w); // V overwrites xn
  __syncthreads();

  // ---- per-token cross-head attention (thread = token t, heads 2p,2p+1) ----
  {
    float qv[32];
    load16(q_us, t, p*32, qv); load16(q_us, t, p*32+16, qv+16);
    float sc[16];
    #pragma unroll
    for (int g8=0; g8<8; ++g8){
      float kv[16]; load16(k_us, t, g8*16, kv);
      float d0=0.f,d1=0.f;
      #pragma unroll
      for (int d=0; d<16; ++d){ d0=fmaf(qv[d],kv[d],d0); d1=fmaf(qv[16+d],kv[d],d1); }
      sc[g8]=d0*0.25f; sc[8+g8]=d1*0.25f;
    }
    #pragma unroll
    for (int hh=0; hh<2; ++hh){
      float mx = sc[hh*8];
      #pragma unroll
      for (int g8=1; g8<8; ++g8) mx = fmaxf(mx, sc[hh*8+g8]);
      float sm=0.f;
      #pragma unroll
      for (int g8=0; g8<8; ++g8){ float e=__expf(sc[hh*8+g8]-mx); sc[hh*8+g8]=e; sm+=e; }
      float inv = 1.f/sm;
      #pragma unroll
      for (int g8=0; g8<8; ++g8) sc[hh*8+g8]*=inv;
    }
    float ov[32];
    #pragma unroll
    for (int i=0;i<32;i++) ov[i]=0.f;
    #pragma unroll
    for (int g8=0; g8<8; ++g8){
      float vv[16]; load16(xn_us, t, g8*16, vv);
      #pragma unroll
      for (int d=0; d<16; ++d){ ov[d]=fmaf(sc[g8],vv[d],ov[d]); ov[16+d]=fmaf(sc[8+g8],vv[d],ov[16+d]); }
    }
    #pragma unroll
    for (int cl=0; cl<4; ++cl){            // attended -> q_us (own cols, safe)
      union { uint4 v; u16 u[8]; } pk;
      #pragma unroll
      for (int j=0;j<8;j++) pk.u[j]=f2b(ov[cl*8+j]);
      int g = p*4+cl;
      *(uint4*)&q_us[(t<<7) + ((g ^ (t&7))<<3)] = pk.v;
    }
  }
  __syncthreads();

  // ---- Wo + residual -> residual2 (regs) + out copy for LN2 (k_us) ----
  zacc(acc); mm128(q_us, ws+OFF_WO, p*2, l, acc);
  #pragma unroll
  for (int mt=0;mt<4;mt++)
  #pragma unroll
  for (int nt=0;nt<2;nt++)
  #pragma unroll
  for (int r=0;r<4;r++){
    int tt = mt*16 + ((l>>4)<<2) + r;
    int cc = n0w + nt*16 + (l&15);
    int i  = mt*8+nt*4+r;
    float v = acc[mt][nt][r] + bias[512+cc] + res[i];
    res[i] = v;                            // residual2 (fp32 in regs)
    k_us[swi(tt,cc)] = f2b(v);
  }
  __syncthreads();

  // ---- LN2 ----
  float ovl[32]; s1=0.f; s2=0.f;
  #pragma unroll
  for (int cl=0; cl<4; ++cl){
    int g = p*4+cl;
    union { uint4 v; u16 u[8]; } pk;
    pk.v = *(const uint4*)&k_us[(t<<7) + ((g ^ (t&7))<<3)];
    #pragma unroll
    for (int j=0;j<8;j++){ float v=b2f(pk.u[j]); ovl[cl*8+j]=v; s1+=v; s2+=v*v; }
  }
  red[p*64+t]=s1; red[256+p*64+t]=s2;
  __syncthreads();
  if (tid < 64){
    float a=0.f,b=0.f;
    #pragma unroll
    for (int i=0;i<4;i++){ a+=red[i*64+tid]; b+=red[256+i*64+tid]; }
    float m=a*0.0078125f, v=b*0.0078125f-m*m;
    stats[tid*2]=m; stats[tid*2+1]=rsqrtf(v+1e-5f);
  }
  __syncthreads();
  {
    float mn=stats[t*2], rs=stats[t*2+1];
    #pragma unroll
    for (int cl=0; cl<4; ++cl){
      union { uint4 v; u16 u[8]; } pk;
      #pragma unroll
      for (int j=0;j<8;j++){ int c=p*32+cl*8+j; pk.u[j]=f2b((ovl[cl*8+j]-mn)*rs*bias[1024+c]+bias[1152+c]); }
      int g = p*4+cl;
      *(uint4*)&xn_us[(t<<7) + ((g ^ (t&7))<<3)] = pk.v;   // hnorm -> xn_us
    }
  }
  __syncthreads();

  // ---- FFN: 4 chunks of 128 cols; FFN2 accumulates in regs ----
  f32x4 acc2[4][2]; zacc(acc2);
  #pragma unroll 1
  for (int ch=0; ch<4; ++ch){
    f32x4 acc1[4][2]; zacc(acc1);
    mm128(xn_us, ws+OFF_W1, ch*8 + p*2, l, acc1);
    #pragma unroll
    for (int mt=0;mt<4;mt++)
    #pragma unroll
    for (int nt=0;nt<2;nt++)
    #pragma unroll
    for (int r=0;r<4;r++){
      int tt = mt*16 + ((l>>4)<<2) + r;
      int cc = n0w + nt*16 + (l&15);
      float v = acc1[mt][nt][r] + bias[1280 + ch*128 + cc];
      k_us[swi(tt,cc)] = f2b(fmaxf(v,0.f));     // relu(h1 chunk)
    }
    __syncthreads();
    mm128_w2(k_us, ws+OFF_W2, p*2, ch, l, acc2);
    __syncthreads();
  }

  // ---- final: + bf2 + residual2, transpose via LDS, coalesced store ----
  float* so = (float*)arena;                    // [64][129] fp32, overlays dead buffers
  #pragma unroll
  for (int mt=0;mt<4;mt++)
  #pragma unroll
  for (int nt=0;nt<2;nt++)
  #pragma unroll
  for (int r=0;r<4;r++){
    int tt = mt*16 + ((l>>4)<<2) + r;
    int cc = n0w + nt*16 + (l&15);
    so[tt*129 + cc] = acc2[mt][nt][r] + bias[640+cc] + res[mt*8+nt*4+r];
  }
  __syncthreads();
  float* ob = out + (size_t)bi*128*DHW + dhw0;
  #pragma unroll
  for (int it=0; it<32; ++it){
    int c = p*32 + it;
    ob[(size_t)c*DHW + t] = so[t*129 + c];
  }
}

extern "C" void kernel_launch(void* const* d_in, const int* in_sizes, int n_in,
                              void* d_out, int out_size, void* d_ws, size_t ws_size,
                              hipStream_t stream){
  const float* x   = (const float*)d_in[0];
  const float* pol = (const float*)d_in[1];
  const float* Wq  = (const float*)d_in[2];
  const float* bq  = (const float*)d_in[3];
  const float* Wk  = (const float*)d_in[4];
  const float* bk  = (const float*)d_in[5];
  const float* Wv  = (const float*)d_in[6];
  const float* bv  = (const float*)d_in[7];
  const float* Wp  = (const float*)d_in[8];
  const float* bp  = (const float*)d_in[9];
  const float* Wo  = (const float*)d_in[10];
  const float* bo  = (const float*)d_in[11];
  const float* g1  = (const float*)d_in[12];
  const float* be1 = (const float*)d_in[13];
  const float* g2  = (const float*)d_in[14];
  const float* be2 = (const float*)d_in[15];
  const float* W1  = (const float*)d_in[16];
  const float* bf1 = (const float*)d_in[17];
  const float* W2  = (const float*)d_in[18];
  const float* bf2 = (const float*)d_in[19];
  u16* ws = (u16*)d_ws;   // needs 384 KB
  pack_w<<<96, 256, 0, stream>>>(Wq, Wk, Wv, Wo, W1, W2, ws);
  fused<<<4096, 256, 0, stream>>>(x, pol, Wp, ws, bp, bq, bk, bv, bo, bf1, bf2,
                                  g1, be1, g2, be2, (float*)d_out);
}

// Round 2
// 470.599 us; speedup vs baseline: 1.0489x; 1.0489x over previous
//
#include <hip/hip_runtime.h>

typedef unsigned short u16;
typedef float f32x4 __attribute__((ext_vector_type(4)));
typedef short bf16x8 __attribute__((ext_vector_type(8)));

#define DHW 131072            // 32*64*64
// packed-weight offsets in ushort units inside d_ws
#define OFF_WQ 0
#define OFF_WK 16384
#define OFF_WV 32768
#define OFF_WO 49152
#define OFF_W1 65536
#define OFF_W2 131072
// total 196608 u16 = 384 KB of d_ws

__device__ __forceinline__ float b2f(u16 u){ union{unsigned i; float f;} x; x.i=((unsigned)u)<<16; return x.f; }
__device__ __forceinline__ u16 f2b(float f){ union{float f; unsigned u;} x; x.f=f; unsigned r=x.u+0x7fffu+((x.u>>16)&1u); return (u16)(r>>16); }
// swizzled u16 offset of channel cch (0..127) in row tok of a [64][128] bf16 buffer (16B cells, cell ^= tok&7)
__device__ __forceinline__ int cofs(int tok, int cch){ return (tok<<7) + ((((cch>>3) ^ (tok&7)))<<3) + (cch&7); }

// ---------------- weight pack kernel: fp32 [K][N] -> bf16 MFMA weight fragments ----------------
// frag (nt,ks): lane l holds W[ks*32 + (l>>4)*8 + j][nt*16 + (l&15)], j=0..7  (valid as A-operand of W^T)
__global__ void pack_w(const float* __restrict__ Wq, const float* __restrict__ Wk,
                       const float* __restrict__ Wv, const float* __restrict__ Wo,
                       const float* __restrict__ W1, const float* __restrict__ W2,
                       u16* __restrict__ ws){
  int tid = blockIdx.x*256 + threadIdx.x;       // 0..24575
  const float* src; int dst, K, N, fb;
  if      (tid <  2048){ src=Wq; dst=OFF_WQ; K=128; N=128; fb=tid;       }
  else if (tid <  4096){ src=Wk; dst=OFF_WK; K=128; N=128; fb=tid-2048;  }
  else if (tid <  6144){ src=Wv; dst=OFF_WV; K=128; N=128; fb=tid-4096;  }
  else if (tid <  8192){ src=Wo; dst=OFF_WO; K=128; N=128; fb=tid-6144;  }
  else if (tid < 16384){ src=W1; dst=OFF_W1; K=128; N=512; fb=tid-8192;  }
  else                 { src=W2; dst=OFF_W2; K=512; N=128; fb=tid-16384; }
  int l = fb & 63, f = fb >> 6;
  int ksc = K >> 5;
  int nt = f / ksc, ks = f - nt*ksc;
  int k0 = ks*32 + ((l>>4)<<3);
  int col = nt*16 + (l&15);
  union { uint4 v; u16 u[8]; } pk;
  #pragma unroll
  for (int j=0;j<8;j++) pk.u[j] = f2b(src[(k0+j)*N + col]);
  *reinterpret_cast<uint4*>(ws + dst + f*512 + l*8) = pk.v;
}

// ---------------- transposed-D micro-GEMM: D[channel][token] = (X @ W)^T ----------------
// acc[tt][cw]: token-tile tt (0..3), channel-tile ctb+cw. C/D: lane&15 = token-in-16, quad*4+r = channel-in-16.
__device__ __forceinline__ void zacc(f32x4 (&a)[4][2]){
  #pragma unroll
  for (int i=0;i<4;i++){ a[i][0]=(f32x4){0.f,0.f,0.f,0.f}; a[i][1]=(f32x4){0.f,0.f,0.f,0.f}; }
}
__device__ __forceinline__ void mmT(const u16* __restrict__ act, const u16* __restrict__ wf,
                                    int ctb, int ksc, int ks0, int l, f32x4 (&acc)[4][2]){
  #pragma unroll
  for (int ks=0; ks<4; ++ks){
    bf16x8 w0 = *(const bf16x8*)(wf + ((ctb+0)*ksc + ks0+ks)*512 + l*8);
    bf16x8 w1 = *(const bf16x8*)(wf + ((ctb+1)*ksc + ks0+ks)*512 + l*8);
    int g = ks*4 + (l>>4);
    #pragma unroll
    for (int tt=0; tt<4; ++tt){
      int tok = tt*16 + (l&15);
      bf16x8 a = *(const bf16x8*)(act + (tok<<7) + ((g ^ (tok&7))<<3));
      acc[tt][0] = __builtin_amdgcn_mfma_f32_16x16x32_bf16(w0, a, acc[tt][0], 0,0,0);
      acc[tt][1] = __builtin_amdgcn_mfma_f32_16x16x32_bf16(w1, a, acc[tt][1], 0,0,0);
    }
  }
}
// pack acc+bias (bf16 bias table, global channel index) into ushort4 per tile
__device__ __forceinline__ void packT(ushort4 (&pk)[4][2], const f32x4 (&acc)[4][2],
                                      const u16* __restrict__ bias, int ctb, int l, bool relu){
  #pragma unroll
  for (int cw=0; cw<2; ++cw){
    int cch = (ctb+cw)*16 + ((l>>4)<<2);
    float b0=b2f(bias[cch]), b1=b2f(bias[cch+1]), b2v=b2f(bias[cch+2]), b3=b2f(bias[cch+3]);
    #pragma unroll
    for (int tt=0; tt<4; ++tt){
      float v0=acc[tt][cw][0]+b0, v1=acc[tt][cw][1]+b1, v2=acc[tt][cw][2]+b2v, v3=acc[tt][cw][3]+b3;
      if (relu){ v0=fmaxf(v0,0.f); v1=fmaxf(v1,0.f); v2=fmaxf(v2,0.f); v3=fmaxf(v3,0.f); }
      pk[tt][cw] = (ushort4){ f2b(v0), f2b(v1), f2b(v2), f2b(v3) };
    }
  }
}
__device__ __forceinline__ void storePK(u16* dst, const ushort4 (&pk)[4][2], int ctb, int l){
  #pragma unroll
  for (int cw=0; cw<2; ++cw){
    int cch = ((ctb+cw)*16 + ((l>>4)<<2)) & 127;   // local channel in [0,128)
    #pragma unroll
    for (int tt=0; tt<4; ++tt){
      int tok = tt*16 + (l&15);
      *(ushort4*)&dst[cofs(tok,cch)] = pk[tt][cw];
    }
  }
}
// read 16 consecutive channels (c0 multiple of 16) of row t into fp32
__device__ __forceinline__ void load16(const u16* buf, int t, int c0, float* o){
  int g = c0 >> 3;
  union { uint4 v; u16 u[8]; } a, b;
  a.v = *(const uint4*)&buf[(t<<7) + (( g    ^ (t&7))<<3)];
  b.v = *(const uint4*)&buf[(t<<7) + (((g+1) ^ (t&7))<<3)];
  #pragma unroll
  for (int j=0;j<8;j++){ o[j]=b2f(a.u[j]); o[8+j]=b2f(b.u[j]); }
}

// ---------------- fused kernel: 1 block = 64 tokens, 256 threads, 4 blocks/CU ----------------
// LDS arena 40448 B: A(16K) + B(16K) + red(2K) + stats(512) + par bf16[2560](5K)
// par: 0 bp |128 g1 |256 be1 |384 g2 |512 be2 |640 Wp[768] |1408 bq |1536 bk |1664 bv |1792 bo |1920 bf2 |2048 bf1[512]
__global__ __launch_bounds__(256,4) void fused(
    const float* __restrict__ x, const float* __restrict__ pol,
    const float* __restrict__ Wp, const u16* __restrict__ ws,
    const float* __restrict__ bp, const float* __restrict__ bq,
    const float* __restrict__ bk, const float* __restrict__ bv,
    const float* __restrict__ bo, const float* __restrict__ bf1,
    const float* __restrict__ bf2, const float* __restrict__ g1,
    const float* __restrict__ be1, const float* __restrict__ g2,
    const float* __restrict__ be2, float* __restrict__ out)
{
  __shared__ __align__(16) unsigned char arena[40448];
  u16*   bufA = (u16*)  (arena);            // xn -> K -> V -> res2(bf16) -> h1 chunks
  u16*   bufB = (u16*)  (arena + 16384);    // xp -> Q -> attended -> hnorm
  float* red   = (float*)(arena + 32768);   // 2048
  float* stats = (float*)(arena + 34816);   // 512
  u16*   par   = (u16*)  (arena + 35328);   // 5120

  const int tid = threadIdx.x;
  const int t   = tid & 63;
  const int p   = __builtin_amdgcn_readfirstlane(tid >> 6);
  const int l   = t;

  // ---- params -> bf16 LDS ----
  for (int i=tid; i<2560; i+=256){
    float v;
    if      (i< 128) v = bp [i];
    else if (i< 256) v = g1 [i-128];
    else if (i< 384) v = be1[i-256];
    else if (i< 512) v = g2 [i-384];
    else if (i< 640) v = be2[i-512];
    else if (i<1408) v = Wp [i-640];
    else if (i<1536) v = bq [i-1408];
    else if (i<1664) v = bk [i-1536];
    else if (i<1792) v = bv [i-1664];
    else if (i<1920) v = bo [i-1792];
    else if (i<2048) v = bf2[i-1920];
    else             v = bf1[i-2048];
    par[i] = f2b(v);
  }
  const int bi   = (int)((blockIdx.x*64) >> 17);
  const int dhw0 = (int)((blockIdx.x*64) & (DHW-1));
  const float* xb = x   + (size_t)bi*128*DHW + dhw0;
  const float* pb = pol + (size_t)bi*6*DHW + dhw0;
  float pl6[6];
  #pragma unroll
  for (int j=0;j<6;j++) pl6[j] = pb[(size_t)j*DHW + t];
  __syncthreads();

  // ---- stage: xp = x + polar@Wp + bp (fp32 regs); LN1 sums; xp -> B (bf16) ----
  float xp[32]; float s1=0.f, s2=0.f;
  #pragma unroll
  for (int it=0; it<32; ++it){
    int c = p*32 + it;
    float a = xb[(size_t)c*DHW + t] + b2f(par[c]);
    #pragma unroll
    for (int j=0;j<6;j++) a = fmaf(pl6[j], b2f(par[640 + j*128 + c]), a);
    xp[it]=a; s1+=a; s2+=a*a;
  }
  #pragma unroll
  for (int cl=0; cl<4; ++cl){
    union { uint4 v; u16 u[8]; } pk;
    #pragma unroll
    for (int j=0;j<8;j++) pk.u[j]=f2b(xp[cl*8+j]);
    *(uint4*)&bufB[(t<<7) + (((p*4+cl) ^ (t&7))<<3)] = pk.v;
  }
  red[p*64+t]=s1; red[256+p*64+t]=s2;
  __syncthreads();
  if (tid < 64){
    float a=0.f,b=0.f;
    #pragma unroll
    for (int i=0;i<4;i++){ a+=red[i*64+tid]; b+=red[256+i*64+tid]; }
    float m=a*0.0078125f, v=b*0.0078125f-m*m;
    stats[tid*2]=m; stats[tid*2+1]=rsqrtf(v+1e-5f);
  }
  __syncthreads();

  // ---- xn = LN1(xp)*g1+be1 -> A;  residual (bf16) from B at D^T coords ----
  {
    float mn=stats[t*2], rs=stats[t*2+1];
    #pragma unroll
    for (int cl=0; cl<4; ++cl){
      union { uint4 v; u16 u[8]; } pk;
      #pragma unroll
      for (int j=0;j<8;j++){ int c=p*32+cl*8+j; pk.u[j]=f2b((xp[cl*8+j]-mn)*rs*b2f(par[128+c])+b2f(par[256+c])); }
      *(uint4*)&bufA[(t<<7) + (((p*4+cl) ^ (t&7))<<3)] = pk.v;
    }
  }
  ushort4 resq[4][2];
  #pragma unroll
  for (int cw=0; cw<2; ++cw){
    int cch = (p*2+cw)*16 + ((l>>4)<<2);
    #pragma unroll
    for (int tt=0; tt<4; ++tt) resq[tt][cw] = *(const ushort4*)&bufB[cofs(tt*16+(l&15), cch)];
  }
  __syncthreads();

  // ---- QKV:  Q -> B,  V -> regs (packed),  K -> A (after sync) ----
  f32x4 acc[4][2]; ushort4 pkt[4][2];
  zacc(acc); mmT(bufA, ws+OFF_WQ, p*2, 4, 0, l, acc);
  packT(pkt, acc, par+1408, p*2, l, false); storePK(bufB, pkt, p*2, l);
  ushort4 pkV[4][2];
  zacc(acc); mmT(bufA, ws+OFF_WV, p*2, 4, 0, l, acc);
  packT(pkV, acc, par+1664, p*2, l, false);
  zacc(acc); mmT(bufA, ws+OFF_WK, p*2, 4, 0, l, acc);
  __syncthreads();                          // all xn reads done
  packT(pkt, acc, par+1536, p*2, l, false); storePK(bufA, pkt, p*2, l);   // K -> A
  __syncthreads();

  // ---- attention scores + softmax (thread = token t, heads 2p,2p+1) ----
  float sc[16];
  {
    float qv[32];
    load16(bufB, t, p*32, qv); load16(bufB, t, p*32+16, qv+16);
    #pragma unroll
    for (int g8=0; g8<8; ++g8){
      float kv[16]; load16(bufA, t, g8*16, kv);
      float d0=0.f,d1=0.f;
      #pragma unroll
      for (int d=0; d<16; ++d){ d0=fmaf(qv[d],kv[d],d0); d1=fmaf(qv[16+d],kv[d],d1); }
      sc[g8]=d0*0.25f; sc[8+g8]=d1*0.25f;
    }
    #pragma unroll
    for (int hh=0; hh<2; ++hh){
      float mx = sc[hh*8];
      #pragma unroll
      for (int g8=1; g8<8; ++g8) mx = fmaxf(mx, sc[hh*8+g8]);
      float sm=0.f;
      #pragma unroll
      for (int g8=0; g8<8; ++g8){ float e=__expf(sc[hh*8+g8]-mx); sc[hh*8+g8]=e; sm+=e; }
      float inv = 1.f/sm;
      #pragma unroll
      for (int g8=0; g8<8; ++g8) sc[hh*8+g8]*=inv;
    }
  }
  __syncthreads();
  storePK(bufA, pkV, p*2, l);               // V -> A (over K)
  __syncthreads();
  {  // PV; attended -> B (own row/cols, no race)
    float ov[32];
    #pragma unroll
    for (int i=0;i<32;i++) ov[i]=0.f;
    #pragma unroll
    for (int g8=0; g8<8; ++g8){
      float vv[16]; load16(bufA, t, g8*16, vv);
      #pragma unroll
      for (int d=0; d<16; ++d){ ov[d]=fmaf(sc[g8],vv[d],ov[d]); ov[16+d]=fmaf(sc[8+g8],vv[d],ov[16+d]); }
    }
    #pragma unroll
    for (int cl=0; cl<4; ++cl){
      union { uint4 v; u16 u[8]; } pk;
      #pragma unroll
      for (int j=0;j<8;j++) pk.u[j]=f2b(ov[cl*8+j]);
      *(uint4*)&bufB[(t<<7) + (((p*4+cl) ^ (t&7))<<3)] = pk.v;
    }
  }
  __syncthreads();

  // ---- Wo + residual -> res2 (packed regs) + bf16 copy in A for LN2 ----
  ushort4 res2q[4][2];
  zacc(acc); mmT(bufB, ws+OFF_WO, p*2, 4, 0, l, acc);
  #pragma unroll
  for (int cw=0; cw<2; ++cw){
    int cch = (p*2+cw)*16 + ((l>>4)<<2);
    float b0=b2f(par[1792+cch]), b1=b2f(par[1793+cch]), b2v=b2f(par[1794+cch]), b3=b2f(par[1795+cch]);
    #pragma unroll
    for (int tt=0; tt<4; ++tt){
      int tok = tt*16 + (l&15);
      ushort4 r4 = resq[tt][cw];
      ushort4 pk = (ushort4){ f2b(acc[tt][cw][0]+b0+b2f(r4.x)),
                              f2b(acc[tt][cw][1]+b1+b2f(r4.y)),
                              f2b(acc[tt][cw][2]+b2v+b2f(r4.z)),
                              f2b(acc[tt][cw][3]+b3+b2f(r4.w)) };
      res2q[tt][cw] = pk;
      *(ushort4*)&bufA[cofs(tok,cch)] = pk;
    }
  }
  __syncthreads();

  // ---- LN2 ----
  float ovl[32]; s1=0.f; s2=0.f;
  #pragma unroll
  for (int cl=0; cl<4; ++cl){
    union { uint4 v; u16 u[8]; } pk;
    pk.v = *(const uint4*)&bufA[(t<<7) + (((p*4+cl) ^ (t&7))<<3)];
    #pragma unroll
    for (int j=0;j<8;j++){ float v=b2f(pk.u[j]); ovl[cl*8+j]=v; s1+=v; s2+=v*v; }
  }
  red[p*64+t]=s1; red[256+p*64+t]=s2;
  __syncthreads();
  if (tid < 64){
    float a=0.f,b=0.f;
    #pragma unroll
    for (int i=0;i<4;i++){ a+=red[i*64+tid]; b+=red[256+i*64+tid]; }
    float m=a*0.0078125f, v=b*0.0078125f-m*m;
    stats[tid*2]=m; stats[tid*2+1]=rsqrtf(v+1e-5f);
  }
  __syncthreads();
  {
    float mn=stats[t*2], rs=stats[t*2+1];
    #pragma unroll
    for (int cl=0; cl<4; ++cl){
      union { uint4 v; u16 u[8]; } pk;
      #pragma unroll
      for (int j=0;j<8;j++){ int c=p*32+cl*8+j; pk.u[j]=f2b((ovl[cl*8+j]-mn)*rs*b2f(par[384+c])+b2f(par[512+c])); }
      *(uint4*)&bufB[(t<<7) + (((p*4+cl) ^ (t&7))<<3)] = pk.v;   // hnorm -> B
    }
  }
  __syncthreads();

  // ---- FFN: 4 chunks of 128 cols; h1 chunk -> A; FFN2 accumulates in regs ----
  f32x4 acc2[4][2]; zacc(acc2);
  #pragma unroll 1
  for (int ch=0; ch<4; ++ch){
    f32x4 acc1[4][2]; zacc(acc1);
    mmT(bufB, ws+OFF_W1, ch*8+p*2, 4, 0, l, acc1);
    packT(pkt, acc1, par+2048, ch*8+p*2, l, true); storePK(bufA, pkt, ch*8+p*2, l);
    __syncthreads();
    mmT(bufA, ws+OFF_W2, p*2, 16, ch*4, l, acc2);
    __syncthreads();
  }

  // ---- final: + bf2 + res2, direct coalesced-chunk stores from regs ----
  float* ob = out + (size_t)bi*128*DHW + dhw0;
  #pragma unroll
  for (int cw=0; cw<2; ++cw){
    int cch = (p*2+cw)*16 + ((l>>4)<<2);
    float b0=b2f(par[1920+cch]), b1=b2f(par[1921+cch]), b2v=b2f(par[1922+cch]), b3=b2f(par[1923+cch]);
    #pragma unroll
    for (int tt=0; tt<4; ++tt){
      int tok = tt*16 + (l&15);
      ushort4 r4 = res2q[tt][cw];
      ob[(size_t)(cch+0)*DHW + tok] = acc2[tt][cw][0] + b0 + b2f(r4.x);
      ob[(size_t)(cch+1)*DHW + tok] = acc2[tt][cw][1] + b1 + b2f(r4.y);
      ob[(size_t)(cch+2)*DHW + tok] = acc2[tt][cw][2] + b2v + b2f(r4.z);
      ob[(size_t)(cch+3)*DHW + tok] = acc2[tt][cw][3] + b3 + b2f(r4.w);
    }
  }
}

extern "C" void kernel_launch(void* const* d_in, const int* in_sizes, int n_in,
                              void* d_out, int out_size, void* d_ws, size_t ws_size,
                              hipStream_t stream){
  const float* x   = (const float*)d_in[0];
  const float* pol = (const float*)d_in[1];
  const float* Wq  = (const float*)d_in[2];
  const float* bq  = (const float*)d_in[3];
  const float* Wk  = (const float*)d_in[4];
  const float* bk  = (const float*)d_in[5];
  const float* Wv  = (const float*)d_in[6];
  const float* bv  = (const float*)d_in[7];
  const float* Wp  = (const float*)d_in[8];
  const float* bp  = (const float*)d_in[9];
  const float* Wo  = (const float*)d_in[10];
  const float* bo  = (const float*)d_in[11];
  const float* g1  = (const float*)d_in[12];
  const float* be1 = (const float*)d_in[13];
  const float* g2  = (const float*)d_in[14];
  const float* be2 = (const float*)d_in[15];
  const float* W1  = (const float*)d_in[16];
  const float* bf1 = (const float*)d_in[17];
  const float* W2  = (const float*)d_in[18];
  const float* bf2 = (const float*)d_in[19];
  u16* ws = (u16*)d_ws;   // needs 384 KB
  pack_w<<<96, 256, 0, stream>>>(Wq, Wk, Wv, Wo, W1, W2, ws);
  fused<<<4096, 256, 0, stream>>>(x, pol, Wp, ws, bp, bq, bk, bv, bo, bf1, bf2,
                                  g1, be1, g2, be2, (float*)d_out);
}